// Round 3
// baseline (366.854 us; speedup 1.0000x reference)
//
#include <hip/hip_runtime.h>
#include <stdint.h>

#define THREADS 256
#define ROWS_PER_BLOCK 256

// Byte-wise dot product with accumulator: a has 4 bytes in [0,15],
// m has 4 bytes in {0,1}. Returns c + sum of selected bytes (<= c+60).
#if __has_builtin(__builtin_amdgcn_udot4)
__device__ __forceinline__ uint32_t dot4acc(uint32_t a, uint32_t m, uint32_t c) {
  return __builtin_amdgcn_udot4(a, m, c, false);
}
#else
__device__ __forceinline__ uint32_t dot4acc(uint32_t a, uint32_t m, uint32_t c) {
  uint32_t mf = m;
  mf |= mf << 1;
  mf |= mf << 2;
  mf |= mf << 4;
  uint32_t t = a & mf;
  uint32_t u = (t & 0xFFFFu) + (t >> 16);   // byte sums <= 30, no carry
  return (u & 0xFFu) + ((u >> 8) & 0xFFu) + c;
}
#endif

// Matches np: clip(round((v - in_min)/rng * 15), 0, 15), round-half-even.
// IEEE fp32 div kept — bit-exact (absmax = 0 in rounds 1 & 2).
__device__ __forceinline__ float quant1(float v, float in_min, float rng) {
  float t = (v - in_min) / rng * 15.0f;
  t = rintf(t);                          // v_rndne_f32 == np.round
  t = fmaxf(t, 0.0f);
  t = fminf(t, 15.0f);
  return t;
}

__device__ __forceinline__ uint32_t quant4(float4 v, float in_min, float rng) {
  uint32_t a = (uint32_t)quant1(v.x, in_min, rng);
  uint32_t b = (uint32_t)quant1(v.y, in_min, rng);
  uint32_t c = (uint32_t)quant1(v.z, in_min, rng);
  uint32_t d = (uint32_t)quant1(v.w, in_min, rng);
  return a | (b << 8) | (c << 16) | (d << 24);
}

__global__ __launch_bounds__(THREADS) void quantlinear_kernel(
    const float* __restrict__ x, const float* __restrict__ weight,
    const float* __restrict__ p_in_max, const float* __restrict__ p_in_min,
    float* __restrict__ out, int rows) {
  // Per-o byte masks (4 groups packed per uint4) + per-o bias.
  __shared__ __align__(16) uint4 sh_mp[32];
  __shared__ __align__(16) uint4 sh_mm[32];
  __shared__ __align__(16) float sh_bias[32];
  // Quantized-input staging: 16 B per row (4 group-dwords). 4 KB.
  __shared__ __align__(16) uint32_t sh_xq[ROWS_PER_BLOCK * 4];

  const float in_max = p_in_max[0];
  const float in_min = p_in_min[0];
  const float rng = in_max - in_min;

  const int t = threadIdx.x;

  // --- weight prep: masks + bias ---
  if (t < 128) {
    const int o = t >> 2, g = t & 3;
    float4 w4 = ((const float4*)weight)[o * 4 + g];
    uint32_t mp = (w4.x > 0.f ? 1u : 0u) | ((w4.y > 0.f ? 1u : 0u) << 8) |
                  ((w4.z > 0.f ? 1u : 0u) << 16) | ((w4.w > 0.f ? 1u : 0u) << 24);
    uint32_t mm = (w4.x < 0.f ? 1u : 0u) | ((w4.y < 0.f ? 1u : 0u) << 8) |
                  ((w4.z < 0.f ? 1u : 0u) << 16) | ((w4.w < 0.f ? 1u : 0u) << 24);
    ((uint32_t*)&sh_mp[o])[g] = mp;
    ((uint32_t*)&sh_mm[o])[g] = mm;
  } else if (t < 160) {
    const int o = t - 128;
    int s = 0;
    for (int i = 0; i < 16; ++i) {
      float w = weight[o * 16 + i];
      s += (w > 0.f) ? 1 : ((w < 0.f) ? -1 : 0);
    }
    sh_bias[o] = in_min * (float)s;  // exact in fp32 here
  }

  // --- Phase A: coalesced load + quantize + stage Xq in LDS ---
  // Block covers ROWS_PER_BLOCK rows = 1024 float4s of input.
  const float4* __restrict__ xv = (const float4*)x;
  const size_t in_base = (size_t)blockIdx.x * (ROWS_PER_BLOCK * 4);
  const size_t in_lim = (size_t)rows * 4;
#pragma unroll
  for (int s = 0; s < 4; ++s) {
    const int i = s * THREADS + t;           // float4 index within block
    const size_t gi = in_base + (size_t)i;   // = row*4 + g, row-major
    if (gi < in_lim) {
      float4 v = xv[gi];
      sh_xq[i] = quant4(v, in_min, rng);     // lane-consecutive dwords: no conflicts
    }
  }
  __syncthreads();

  // --- Phase B: transposed compute, naturally-coalesced stores ---
  // Thread t owns output column c = t&7 (outputs o in [4c, 4c+4)) for rows
  // r = (t>>3) + 32*s, s = 0..7. Store index = out_base + s*256 + t (float4).
  const int c = t & 7;

  // Hoist this thread's masks + bias into registers (broadcast b128 reads).
  uint4 mp0 = sh_mp[4 * c + 0], mm0 = sh_mm[4 * c + 0];
  uint4 mp1 = sh_mp[4 * c + 1], mm1 = sh_mm[4 * c + 1];
  uint4 mp2 = sh_mp[4 * c + 2], mm2 = sh_mm[4 * c + 2];
  uint4 mp3 = sh_mp[4 * c + 3], mm3 = sh_mm[4 * c + 3];
  float4 bias4 = ((const float4*)sh_bias)[c];

  float4* __restrict__ outv = (float4*)out;
  const size_t out_base = (size_t)blockIdx.x * (ROWS_PER_BLOCK * 8);
  const size_t out_lim = (size_t)rows * 8;
  const uint4* sh_xq_v = (const uint4*)sh_xq;

#pragma unroll
  for (int s = 0; s < 8; ++s) {
    const int r = (t >> 3) + 32 * s;
    uint4 Xq = sh_xq_v[r];  // 8-lane broadcast per address, conflict-free

    // round(y/15) for integer y in [0,60] == floor((y+7)/15)
    // == ((y+7)*1093) >> 14. The +7 rides in the dot4 accumulator.
    // clip(-4,4) is automatic (each plane's requant is in [0,4]).
    float res[4];
#pragma unroll
    for (int j = 0; j < 4; ++j) {
      const uint4 mp = (j == 0) ? mp0 : (j == 1) ? mp1 : (j == 2) ? mp2 : mp3;
      const uint4 mm = (j == 0) ? mm0 : (j == 1) ? mm1 : (j == 2) ? mm2 : mm3;
      int acc = 0;
      {
        uint32_t yp7, ym7;
        yp7 = dot4acc(Xq.x, mp.x, 7u); ym7 = dot4acc(Xq.x, mm.x, 7u);
        acc += (int)((yp7 * 1093u) >> 14) - (int)((ym7 * 1093u) >> 14);
        yp7 = dot4acc(Xq.y, mp.y, 7u); ym7 = dot4acc(Xq.y, mm.y, 7u);
        acc += (int)((yp7 * 1093u) >> 14) - (int)((ym7 * 1093u) >> 14);
        yp7 = dot4acc(Xq.z, mp.z, 7u); ym7 = dot4acc(Xq.z, mm.z, 7u);
        acc += (int)((yp7 * 1093u) >> 14) - (int)((ym7 * 1093u) >> 14);
        yp7 = dot4acc(Xq.w, mp.w, 7u); ym7 = dot4acc(Xq.w, mm.w, 7u);
        acc += (int)((yp7 * 1093u) >> 14) - (int)((ym7 * 1093u) >> 14);
      }
      const float b = (j == 0) ? bias4.x : (j == 1) ? bias4.y
                     : (j == 2) ? bias4.z : bias4.w;
      res[j] = fmaf((float)acc, rng, b);  // exact: integer multiples of rng + bias
    }

    const size_t gi = out_base + (size_t)(s * THREADS + t);
    if (gi < out_lim)
      outv[gi] = make_float4(res[0], res[1], res[2], res[3]);
  }
}

extern "C" void kernel_launch(void* const* d_in, const int* in_sizes, int n_in,
                              void* d_out, int out_size, void* d_ws, size_t ws_size,
                              hipStream_t stream) {
  const float* x = (const float*)d_in[0];
  const float* w = (const float*)d_in[1];
  // d_in[2] is `scale` — unused in the forward pass.
  const float* in_max = (const float*)d_in[3];
  const float* in_min = (const float*)d_in[4];
  float* out = (float*)d_out;

  const int rows = in_sizes[0] / 16;  // B
  const int blocks = (rows + ROWS_PER_BLOCK - 1) / ROWS_PER_BLOCK;  // 8192
  quantlinear_kernel<<<blocks, THREADS, 0, stream>>>(x, w, in_max, in_min, out,
                                                     rows);
}